// Round 4
// baseline (243.655 us; speedup 1.0000x reference)
//
#include <hip/hip_runtime.h>
#include <hip/hip_bf16.h>

#define B_SZ 4
#define NHEADS 16
#define T_SZ 2048
#define DE 1024
#define DH 64
#define BH (B_SZ*NHEADS)
#define SCL 0.18033688011112042f  /* 0.125 * log2(e) */
#define PSTR 88   /* P-buffer stride in shorts: 176 B = 16-aligned, 44 dw == 12 mod 32 -> 2-way (free) */

typedef __attribute__((ext_vector_type(8))) short short8;   // 8 bf16 = 4 VGPRs
typedef __attribute__((ext_vector_type(4))) float float4v;
typedef __attribute__((ext_vector_type(2))) unsigned int uint2v;

__device__ __forceinline__ short f2bf(float f) {
    __hip_bfloat16 h = __float2bfloat16(f);
    return *reinterpret_cast<short*>(&h);
}
__device__ __forceinline__ unsigned int pack_bf2(float a, float b) {
    float2 f; f.x = a; f.y = b;
    __hip_bfloat162 h = __float22bfloat162_rn(f);
    return *reinterpret_cast<unsigned int*>(&h);
}
__device__ __forceinline__ float4v zero4() {
    float4v z = {0.f, 0.f, 0.f, 0.f};
    return z;
}
// XOR-swizzled stride-64 LDS tile. g is the LOGICAL 8-element column group;
// physical slot is g ^ (row & 7). Pass logical coords to BOTH stores and loads
// (reg-staged ds_write path), or pre-swizzle the global source when staging
// via global_load_lds (linear dest, rule #21 / m173 pattern).
__device__ __forceinline__ int swz(int row, int g) {
    return row * 64 + (((g) ^ (row & 7)) << 3);
}
// async 16B global -> LDS (linear dest: wave-uniform base + lane*16)
__device__ __forceinline__ void gl_lds16(const short* g, short* l) {
    __builtin_amdgcn_global_load_lds(
        (const __attribute__((address_space(1))) void*)g,
        (__attribute__((address_space(3))) void*)l, 16, 0, 0);
}

// ---- transpose+downcast: fp32 src[R][C] -> bf16 dst[C][R], batched over z ---
__global__ __launch_bounds__(256) void transpose_k(const float* __restrict__ src,
                                                   short* __restrict__ dst,
                                                   int R, int C) {
    __shared__ __align__(16) short tile[64 * 65];
    int c0 = blockIdx.x * 64, r0 = blockIdx.y * 64;
    src += (size_t)blockIdx.z * R * C;
    dst += (size_t)blockIdx.z * R * C;
    int tid = threadIdx.x;
#pragma unroll
    for (int it = 0; it < 16; ++it) {
        int idx = it * 256 + tid;
        int rr = idx >> 6, cc = idx & 63;
        tile[cc * 65 + rr] = f2bf(src[(size_t)(r0 + rr) * C + c0 + cc]);
    }
    __syncthreads();
#pragma unroll
    for (int it = 0; it < 16; ++it) {
        int idx = it * 256 + tid;
        int cc = idx >> 6, rr = idx & 63;
        dst[(size_t)(c0 + cc) * R + r0 + rr] = tile[cc * 65 + rr];
    }
}

// ------ QKV projection + q/k norm: M=128 x N=128 (2 heads), 2-phase dbuf -----
// Grid (64, 24) = 1536 blocks = exactly 3 rounds at 2 blocks/CU (64 KB LDS).
// K-loop: STAGE(t+1) issued BEFORE COMPUTE(t), ONE __syncthreads per K-step —
// its implicit vmcnt(0) is the wait for the prefetched buffer; loads fly under
// the 32 MFMAs. (This structure took qkv_k 108 -> <95 us in round 3.)
// XT: [b][t][d] bf16 ; WT: [n][h*64+e][d] bf16
// Qw (pre-scaled by SCL), Kw: [bh][t][e] ; Vt: [bh][e][t]
__global__ __launch_bounds__(256, 2) void qkv_k(const short* __restrict__ XT,
                                                const short* __restrict__ WT,
                                                short* __restrict__ Qw,
                                                short* __restrict__ Kw,
                                                short* __restrict__ Vt) {
    __shared__ __align__(16) short ldsA[2][128 * 64];   // 2 x 16 KB, swizzled
    __shared__ __align__(16) short ldsB[2][128 * 64];   // 2 x 16 KB, swizzled
    int b  = blockIdx.x >> 4;                        // grid.x = 64: same-A blocks
    int t0 = (blockIdx.x & 15) * 128;                //   share XCD (x mod 8 const in y)
    int n  = blockIdx.y >> 3;
    int h0 = (blockIdx.y & 7) * 2;                   // 2 heads per block
    int tid = threadIdx.x, wave = tid >> 6, lane = tid & 63;
    int l15 = lane & 15, quad = lane >> 4;
    int wr = wave >> 1, wc = wave & 1;               // 2x2 wave grid

    const short* Arow = XT + ((size_t)b * T_SZ + t0) * DE;
    const short* Brow = WT + ((size_t)n * 1024 + h0 * 64) * DE;

    // per-lane pre-swizzle for global_load_lds staging
    int rA = lane >> 3;                   // row within the wave's 8-row stripe
    int gl = (lane & 7) ^ rA;             // logical column group for this slot

    float4v acc[4][4];
#pragma unroll
    for (int mm = 0; mm < 4; ++mm)
#pragma unroll
        for (int j = 0; j < 4; ++j) acc[mm][j] = zero4();

    auto STAGE = [&](short* La, short* Lb, int k0) {
#pragma unroll
        for (int it = 0; it < 4; ++it) {       // A,B: 128 rows, 8 rows/wave/issue
            int rowbase = it * 32 + wave * 8;
            gl_lds16(&Arow[(size_t)(rowbase + rA) * DE + k0 + gl * 8],
                     &La[(it * 256 + wave * 64) * 8]);
            gl_lds16(&Brow[(size_t)(rowbase + rA) * DE + k0 + gl * 8],
                     &Lb[(it * 256 + wave * 64) * 8]);
        }
    };
    auto COMPUTE = [&](const short* La, const short* Lb) {
#pragma unroll
        for (int ks = 0; ks < 2; ++ks) {
            short8 af[4], bf[4];
#pragma unroll
            for (int mm = 0; mm < 4; ++mm)
                af[mm] = *(const short8*)&La[swz(64 * wr + 16 * mm + l15, 4 * ks + quad)];
#pragma unroll
            for (int j = 0; j < 4; ++j)
                bf[j] = *(const short8*)&Lb[swz(64 * wc + 16 * j + l15, 4 * ks + quad)];
#pragma unroll
            for (int mm = 0; mm < 4; ++mm)
#pragma unroll
                for (int j = 0; j < 4; ++j)
                    acc[mm][j] = __builtin_amdgcn_mfma_f32_16x16x32_bf16(af[mm], bf[j], acc[mm][j], 0, 0, 0);
        }
    };

    STAGE(ldsA[0], ldsB[0], 0);
    __syncthreads();
    for (int k0 = 0; k0 < DE; k0 += 128) {     // 8 iters, 2 K-steps each
        STAGE(ldsA[1], ldsB[1], k0 + 64);      // k0+64 <= 960 always in-range
        COMPUTE(ldsA[0], ldsB[0]);
        __syncthreads();                       // drains prefetch + my ds_reads
        if (k0 + 128 < DE)
            STAGE(ldsA[0], ldsB[0], k0 + 128);
        COMPUTE(ldsA[1], ldsB[1]);
        __syncthreads();
    }

    // epilogue: wave owns one head (wc); per 16-row subtile mm
    int h = h0 + wc;
    int bh = b * NHEADS + h;
#pragma unroll
    for (int mm = 0; mm < 4; ++mm) {
        int tbase = t0 + 64 * wr + 16 * mm;
        if (n < 2) {
            float oscale = (n == 0) ? SCL : 1.0f;
            float mu[4], inv[4];
#pragma unroll
            for (int r = 0; r < 4; ++r) {
                float s1 = 0.f, s2 = 0.f;
#pragma unroll
                for (int jj = 0; jj < 4; ++jj) {
                    float v = acc[mm][jj][r];
                    s1 += v; s2 += v * v;
                }
                for (int sh = 1; sh < 16; sh <<= 1) {
                    s1 += __shfl_xor(s1, sh, 64);
                    s2 += __shfl_xor(s2, sh, 64);
                }
                mu[r] = s1 * (1.0f / 64.0f);
                float var = (s2 - 64.0f * mu[r] * mu[r]) * (1.0f / 63.0f);
                var = fmaxf(var, 0.0f);
                inv[r] = oscale / (sqrtf(var) + 1e-5f);
            }
            short* dst = (n == 0 ? Qw : Kw) + (size_t)bh * T_SZ * DH;
#pragma unroll
            for (int r = 0; r < 4; ++r) {
                int t = tbase + quad * 4 + r;
#pragma unroll
                for (int jj = 0; jj < 4; ++jj) {
                    float v = (acc[mm][jj][r] - mu[r]) * inv[r];
                    dst[(size_t)t * DH + 16 * jj + l15] = f2bf(v);
                }
            }
        } else {
#pragma unroll
            for (int r = 0; r < 4; ++r) {
                int t = tbase + quad * 4 + r;
#pragma unroll
                for (int jj = 0; jj < 4; ++jj) {
                    Vt[((size_t)bh * DH + 16 * jj + l15) * T_SZ + t] =
                        f2bf(acc[mm][jj][r]);
                }
            }
        }
    }
}

// ---------------- flash attention (32 q-rows/wave, MFMA l-sum) ---------------
// Grid (x=bh=64, y=tq=16): 1024 blocks = 4 blocks/CU at 38.9 KB LDS -> 16 w/CU.
// Round-1 evidence: occupancy x2 gave only -4% -> chain-bound, not wave-bound.
// This version attacks the per-tile serial chain:
//  (a) T14 async-STAGE split: K/V of tile t+1 -> REGISTERS before compute(t);
//      swizzled ds_write after the post-compute barrier. L2 latency (~300cy)
//      hides under QK+PV instead of being drained at a barrier every tile.
//  (b) P stride 72->88 shorts: 36 dw == 4 (mod 32) made pf b128 reads an 8-way
//      bank conflict (the 6.4M SQ_LDS_BANK_CONFLICT); 44 dw == 12 (mod 32) is
//      2-way = free. 176 B keeps 16-byte alignment for b64 writes/b128 reads.
// Qw (pre-scaled), Kw: [bh][t][e] ; Vt: [bh][e][t]  (bf16) ; out: fp32 [b][h*64+e][t]
// |q.k*SCL| <= 11.4 -> exp2 never overflows; no max subtraction needed.
__global__ __launch_bounds__(256, 4) void attn_k(const short* __restrict__ Qw,
                                                 const short* __restrict__ Kw,
                                                 const short* __restrict__ Vt,
                                                 float* __restrict__ out) {
    __shared__ __align__(16) char smem[38912];
    short* ldsK = (short*)smem;                 // [s][e] 64x64 swizzled (8 KB)
    short* ldsV = (short*)(smem + 8192);        // [e][s] 64x64 swizzled (8 KB)
    short* ldsP = (short*)(smem + 16384);       // per-wave [t][s] 32xPSTR (5.5 KB ea)
    float* ldsO = (float*)smem;                 // epilogue alias: 2 x (64e x 36t fp32)

    int bh = blockIdx.x;
    int t0 = blockIdx.y * 128;
    int b = bh >> 4, h = bh & 15;
    int tid = threadIdx.x, wave = tid >> 6, lane = tid & 63;
    int l15 = lane & 15, quad = lane >> 4;
    int tw = t0 + 32 * wave;                    // this wave's 32 q-rows

    const short* Qp = Qw + (size_t)bh * T_SZ * DH;
    const short* Kp = Kw + (size_t)bh * T_SZ * DH;
    const short* Vp = Vt + (size_t)bh * DH * T_SZ;
    short* Pw = ldsP + wave * 32 * PSTR;

    // reg-staging lane geometry (LOGICAL column group; swz() applied at ds_write)
    int rA = lane >> 3;                // row within the wave's 8-row stripe
    int g8 = lane & 7;

    short8 qf[2][2];   // B-operand: lane holds Q[t=tw+16tt+l15][e=ks*32+quad*8..+7]
#pragma unroll
    for (int tt = 0; tt < 2; ++tt)
#pragma unroll
        for (int ks = 0; ks < 2; ++ks)
            qf[tt][ks] = *(const short8*)&Qp[(size_t)(tw + 16 * tt + l15) * DH + ks * 32 + quad * 8];

    const short one_bf = (short)0x3F80;         // bf16 1.0
    short8 ones = {one_bf, one_bf, one_bf, one_bf, one_bf, one_bf, one_bf, one_bf};

    float4v o[2][4];   // [tt][j: e-subtile]
    float4v ol[2];     // row-sum accumulators (same C-layout rows as o)
#pragma unroll
    for (int tt = 0; tt < 2; ++tt) {
        ol[tt] = zero4();
#pragma unroll
        for (int j = 0; j < 4; ++j) o[tt][j] = zero4();
    }

    short8 rk[2], rv[2];                        // in-flight K/V tile (16 VGPR)
    auto LOADNEXT = [&](int s) {                // issue global loads -> regs
#pragma unroll
        for (int it = 0; it < 2; ++it) {
            int rowbase = it * 32 + wave * 8;
            rk[it] = *(const short8*)&Kp[(size_t)(s + rowbase + rA) * DH + g8 * 8];
            rv[it] = *(const short8*)&Vp[(size_t)(rowbase + rA) * T_SZ + s + g8 * 8];
        }
    };
    auto WRITESTAGE = [&]() {                   // regs -> swizzled LDS
#pragma unroll
        for (int it = 0; it < 2; ++it) {
            int rowbase = it * 32 + wave * 8;
            *(short8*)&ldsK[swz(rowbase + rA, g8)] = rk[it];
            *(short8*)&ldsV[swz(rowbase + rA, g8)] = rv[it];
        }
    };

    LOADNEXT(0);
    WRITESTAGE();
    __syncthreads();

    for (int s0 = 0; s0 < T_SZ; s0 += 64) {
        int sn = (s0 + 64 < T_SZ) ? s0 + 64 : 0;   // last iter: harmless reload
        LOADNEXT(sn);                               // flies under this tile's compute

        // S^T = K.Q^T: C[row=s_local][col=t_local]; lane's 4 regs = 4 consecutive s
#pragma unroll
        for (int j = 0; j < 4; ++j) {
            short8 k0 = *(const short8*)&ldsK[swz(16 * j + l15, quad)];
            short8 k1 = *(const short8*)&ldsK[swz(16 * j + l15, 4 + quad)];
#pragma unroll
            for (int tt = 0; tt < 2; ++tt) {
                float4v z = zero4();
                z = __builtin_amdgcn_mfma_f32_16x16x32_bf16(k0, qf[tt][0], z, 0, 0, 0);
                z = __builtin_amdgcn_mfma_f32_16x16x32_bf16(k1, qf[tt][1], z, 0, 0, 0);
                float p0 = __builtin_amdgcn_exp2f(z[0]);
                float p1 = __builtin_amdgcn_exp2f(z[1]);
                float p2 = __builtin_amdgcn_exp2f(z[2]);
                float p3 = __builtin_amdgcn_exp2f(z[3]);
                uint2v u = { pack_bf2(p0, p1), pack_bf2(p2, p3) };
                // P[t=16tt+l15][s=16j+quad*4 .. +3] — this wave's private region
                *(uint2v*)&Pw[(16 * tt + l15) * PSTR + 16 * j + quad * 4] = u;
            }
        }

        // PV: A = P[t][s], B = V^T[e][s]; l-sum via ones-B MFMA (same A frags)
        short8 pf[2][2];
#pragma unroll
        for (int tt = 0; tt < 2; ++tt) {
            pf[tt][0] = *(const short8*)&Pw[(16 * tt + l15) * PSTR + quad * 8];
            pf[tt][1] = *(const short8*)&Pw[(16 * tt + l15) * PSTR + 32 + quad * 8];
            ol[tt] = __builtin_amdgcn_mfma_f32_16x16x32_bf16(pf[tt][0], ones, ol[tt], 0, 0, 0);
            ol[tt] = __builtin_amdgcn_mfma_f32_16x16x32_bf16(pf[tt][1], ones, ol[tt], 0, 0, 0);
        }
#pragma unroll
        for (int j = 0; j < 4; ++j) {
            short8 v0 = *(const short8*)&ldsV[swz(16 * j + l15, quad)];
            short8 v1 = *(const short8*)&ldsV[swz(16 * j + l15, 4 + quad)];
#pragma unroll
            for (int tt = 0; tt < 2; ++tt) {
                o[tt][j] = __builtin_amdgcn_mfma_f32_16x16x32_bf16(pf[tt][0], v0, o[tt][j], 0, 0, 0);
                o[tt][j] = __builtin_amdgcn_mfma_f32_16x16x32_bf16(pf[tt][1], v1, o[tt][j], 0, 0, 0);
            }
        }

        __syncthreads();     // all waves done reading K/V tile; vmcnt(0) drained here
        WRITESTAGE();        // regs -> LDS for next tile (cheap: ds_writes only)
        __syncthreads();     // next tile visible to all waves
    }

    // rinv: ol[tt][r] is l for t = tw+16tt+quad*4+r — same lane-mapping as o[tt][j][r]
    float4v rinv[2];
#pragma unroll
    for (int tt = 0; tt < 2; ++tt)
#pragma unroll
        for (int r = 0; r < 4; ++r)
            rinv[tt][r] = 1.0f / ol[tt][r];

    // epilogue: normalize, transpose via LDS (2 phases x 2 waves), float4 stores
#pragma unroll
    for (int ph = 0; ph < 2; ++ph) {
        __syncthreads();
        if ((wave >> 1) == ph) {
            float* Ow = ldsO + (wave & 1) * (64 * 36);
#pragma unroll
            for (int tt = 0; tt < 2; ++tt)
#pragma unroll
                for (int j = 0; j < 4; ++j) {
                    float4v ov = o[tt][j] * rinv[tt];
                    // O[t = 32w + 16tt+quad*4+r][e = 16j+l15]
                    *(float4v*)&Ow[(16 * j + l15) * 36 + 16 * tt + quad * 4] = ov;
                }
        }
        __syncthreads();
#pragma unroll
        for (int it = 0; it < 4; ++it) {
            int idx = it * 256 + tid;          // 1024 float4 = 2 regions x 64e x 32t
            int rg = idx >> 9;
            int rid = idx & 511;
            int e = rid >> 3, t4 = (rid & 7) * 4;
            *(float4v*)&out[((size_t)(b * DE + h * DH + e)) * T_SZ + t0 + 32 * (2 * ph + rg) + t4] =
                *(const float4v*)&ldsO[rg * (64 * 36) + e * 36 + t4];
        }
    }
}

extern "C" void kernel_launch(void* const* d_in, const int* in_sizes, int n_in,
                              void* d_out, int out_size, void* d_ws, size_t ws_size,
                              hipStream_t stream) {
    const float* x = (const float*)d_in[0];   // fp32 [B][D][T]
    const float* w = (const float*)d_in[1];   // fp32 [3][H][D][dh]
    float* out = (float*)d_out;               // fp32 [B][D][T]
    char* ws = (char*)d_ws;

    const size_t XT_BYTES = (size_t)B_SZ * T_SZ * DE * 2;       // 16.8 MB (bf16)
    const size_t WT_BYTES = (size_t)3 * NHEADS * DH * DE * 2;   // 6.3 MB
    const size_t QKV_BYTES = (size_t)BH * T_SZ * DH * 2;        // 16.8 MB each

    short* XT = (short*)(ws);
    short* WT = (short*)(ws + XT_BYTES);
    short* Qw = (short*)(ws + XT_BYTES + WT_BYTES);
    short* Kw = (short*)(ws + XT_BYTES + WT_BYTES + QKV_BYTES);
    short* Vt = (short*)(ws + XT_BYTES + WT_BYTES + 2 * QKV_BYTES);

    // x: per-b fp32 [D][T] -> bf16 XT [T][D]
    transpose_k<<<dim3(T_SZ / 64, DE / 64, B_SZ), 256, 0, stream>>>(x, XT, DE, T_SZ);
    // w: per-nh fp32 [D][dh] -> bf16 WT [nh][e][D]
    transpose_k<<<dim3(1, DE / 64, 3 * NHEADS), 256, 0, stream>>>(w, WT, DE, DH);
    qkv_k<<<dim3(64, 24), 256, 0, stream>>>(XT, WT, Qw, Kw, Vt);
    attn_k<<<dim3(BH, T_SZ / 128), 256, 0, stream>>>(Qw, Kw, Vt, out);
}

// Round 5
// 237.380 us; speedup vs baseline: 1.0264x; 1.0264x over previous
//
#include <hip/hip_runtime.h>
#include <hip/hip_bf16.h>

#define B_SZ 4
#define NHEADS 16
#define T_SZ 2048
#define DE 1024
#define DH 64
#define BH (B_SZ*NHEADS)
#define SCL 0.18033688011112042f  /* 0.125 * log2(e) */

typedef __attribute__((ext_vector_type(8))) short short8;   // 8 bf16 = 4 VGPRs
typedef __attribute__((ext_vector_type(4))) float float4v;
typedef __attribute__((ext_vector_type(16))) float f32x16;
typedef __attribute__((ext_vector_type(2))) unsigned int uint2v;
typedef __attribute__((ext_vector_type(4))) unsigned int uint4v;

__device__ __forceinline__ short f2bf(float f) {
    __hip_bfloat16 h = __float2bfloat16(f);
    return *reinterpret_cast<short*>(&h);
}
__device__ __forceinline__ unsigned int pack_bf2(float a, float b) {
    float2 f; f.x = a; f.y = b;
    __hip_bfloat162 h = __float22bfloat162_rn(f);
    return *reinterpret_cast<unsigned int*>(&h);
}
__device__ __forceinline__ float4v zero4() {
    float4v z = {0.f, 0.f, 0.f, 0.f};
    return z;
}
// XOR-swizzled stride-64 LDS tile. g is the LOGICAL 8-element column group;
// physical slot is g ^ (row & 7). Pass logical coords to BOTH stores and loads
// (reg-staged ds_write path), or pre-swizzle the global source when staging
// via global_load_lds (linear dest, rule #21 / m173 pattern).
__device__ __forceinline__ int swz(int row, int g) {
    return row * 64 + (((g) ^ (row & 7)) << 3);
}
// async 16B global -> LDS (linear dest: wave-uniform base + lane*16)
__device__ __forceinline__ void gl_lds16(const short* g, short* l) {
    __builtin_amdgcn_global_load_lds(
        (const __attribute__((address_space(1))) void*)g,
        (__attribute__((address_space(3))) void*)l, 16, 0, 0);
}

// ---- transpose+downcast: fp32 src[R][C] -> bf16 dst[C][R], batched over z ---
__global__ __launch_bounds__(256) void transpose_k(const float* __restrict__ src,
                                                   short* __restrict__ dst,
                                                   int R, int C) {
    __shared__ __align__(16) short tile[64 * 65];
    int c0 = blockIdx.x * 64, r0 = blockIdx.y * 64;
    src += (size_t)blockIdx.z * R * C;
    dst += (size_t)blockIdx.z * R * C;
    int tid = threadIdx.x;
#pragma unroll
    for (int it = 0; it < 16; ++it) {
        int idx = it * 256 + tid;
        int rr = idx >> 6, cc = idx & 63;
        tile[cc * 65 + rr] = f2bf(src[(size_t)(r0 + rr) * C + c0 + cc]);
    }
    __syncthreads();
#pragma unroll
    for (int it = 0; it < 16; ++it) {
        int idx = it * 256 + tid;
        int cc = idx >> 6, rr = idx & 63;
        dst[(size_t)(c0 + cc) * R + r0 + rr] = tile[cc * 65 + rr];
    }
}

// ------ QKV projection + q/k norm: M=128 x N=128 (2 heads), 2-phase dbuf -----
// Grid (64, 24) = 1536 blocks = exactly 3 rounds at 2 blocks/CU (64 KB LDS).
// K-loop: STAGE(t+1) issued BEFORE COMPUTE(t), ONE __syncthreads per K-step.
// XT: [b][t][d] bf16 ; WT: [n][h*64+e][d] bf16
// Qw (pre-scaled by SCL), Kw: [bh][t][e] ; Vt: [bh][e][t]
__global__ __launch_bounds__(256, 2) void qkv_k(const short* __restrict__ XT,
                                                const short* __restrict__ WT,
                                                short* __restrict__ Qw,
                                                short* __restrict__ Kw,
                                                short* __restrict__ Vt) {
    __shared__ __align__(16) short ldsA[2][128 * 64];   // 2 x 16 KB, swizzled
    __shared__ __align__(16) short ldsB[2][128 * 64];   // 2 x 16 KB, swizzled
    int b  = blockIdx.x >> 4;                        // grid.x = 64: same-A blocks
    int t0 = (blockIdx.x & 15) * 128;                //   share XCD (x mod 8 const in y)
    int n  = blockIdx.y >> 3;
    int h0 = (blockIdx.y & 7) * 2;                   // 2 heads per block
    int tid = threadIdx.x, wave = tid >> 6, lane = tid & 63;
    int l15 = lane & 15, quad = lane >> 4;
    int wr = wave >> 1, wc = wave & 1;               // 2x2 wave grid

    const short* Arow = XT + ((size_t)b * T_SZ + t0) * DE;
    const short* Brow = WT + ((size_t)n * 1024 + h0 * 64) * DE;

    // per-lane pre-swizzle for global_load_lds staging
    int rA = lane >> 3;                   // row within the wave's 8-row stripe
    int gl = (lane & 7) ^ rA;             // logical column group for this slot

    float4v acc[4][4];
#pragma unroll
    for (int mm = 0; mm < 4; ++mm)
#pragma unroll
        for (int j = 0; j < 4; ++j) acc[mm][j] = zero4();

    auto STAGE = [&](short* La, short* Lb, int k0) {
#pragma unroll
        for (int it = 0; it < 4; ++it) {       // A,B: 128 rows, 8 rows/wave/issue
            int rowbase = it * 32 + wave * 8;
            gl_lds16(&Arow[(size_t)(rowbase + rA) * DE + k0 + gl * 8],
                     &La[(it * 256 + wave * 64) * 8]);
            gl_lds16(&Brow[(size_t)(rowbase + rA) * DE + k0 + gl * 8],
                     &Lb[(it * 256 + wave * 64) * 8]);
        }
    };
    auto COMPUTE = [&](const short* La, const short* Lb) {
#pragma unroll
        for (int ks = 0; ks < 2; ++ks) {
            short8 af[4], bf[4];
#pragma unroll
            for (int mm = 0; mm < 4; ++mm)
                af[mm] = *(const short8*)&La[swz(64 * wr + 16 * mm + l15, 4 * ks + quad)];
#pragma unroll
            for (int j = 0; j < 4; ++j)
                bf[j] = *(const short8*)&Lb[swz(64 * wc + 16 * j + l15, 4 * ks + quad)];
#pragma unroll
            for (int mm = 0; mm < 4; ++mm)
#pragma unroll
                for (int j = 0; j < 4; ++j)
                    acc[mm][j] = __builtin_amdgcn_mfma_f32_16x16x32_bf16(af[mm], bf[j], acc[mm][j], 0, 0, 0);
        }
    };

    STAGE(ldsA[0], ldsB[0], 0);
    __syncthreads();
    for (int k0 = 0; k0 < DE; k0 += 128) {     // 8 iters, 2 K-steps each
        STAGE(ldsA[1], ldsB[1], k0 + 64);      // k0+64 <= 960 always in-range
        COMPUTE(ldsA[0], ldsB[0]);
        __syncthreads();                       // drains prefetch + my ds_reads
        if (k0 + 128 < DE)
            STAGE(ldsA[0], ldsB[0], k0 + 128);
        COMPUTE(ldsA[1], ldsB[1]);
        __syncthreads();
    }

    // epilogue: wave owns one head (wc); per 16-row subtile mm
    int h = h0 + wc;
    int bh = b * NHEADS + h;
#pragma unroll
    for (int mm = 0; mm < 4; ++mm) {
        int tbase = t0 + 64 * wr + 16 * mm;
        if (n < 2) {
            float oscale = (n == 0) ? SCL : 1.0f;
            float mu[4], inv[4];
#pragma unroll
            for (int r = 0; r < 4; ++r) {
                float s1 = 0.f, s2 = 0.f;
#pragma unroll
                for (int jj = 0; jj < 4; ++jj) {
                    float v = acc[mm][jj][r];
                    s1 += v; s2 += v * v;
                }
                for (int sh = 1; sh < 16; sh <<= 1) {
                    s1 += __shfl_xor(s1, sh, 64);
                    s2 += __shfl_xor(s2, sh, 64);
                }
                mu[r] = s1 * (1.0f / 64.0f);
                float var = (s2 - 64.0f * mu[r] * mu[r]) * (1.0f / 63.0f);
                var = fmaxf(var, 0.0f);
                inv[r] = oscale / (sqrtf(var) + 1e-5f);
            }
            short* dst = (n == 0 ? Qw : Kw) + (size_t)bh * T_SZ * DH;
#pragma unroll
            for (int r = 0; r < 4; ++r) {
                int t = tbase + quad * 4 + r;
#pragma unroll
                for (int jj = 0; jj < 4; ++jj) {
                    float v = (acc[mm][jj][r] - mu[r]) * inv[r];
                    dst[(size_t)t * DH + 16 * jj + l15] = f2bf(v);
                }
            }
        } else {
#pragma unroll
            for (int r = 0; r < 4; ++r) {
                int t = tbase + quad * 4 + r;
#pragma unroll
                for (int jj = 0; jj < 4; ++jj) {
                    Vt[((size_t)bh * DH + 16 * jj + l15) * T_SZ + t] =
                        f2bf(acc[mm][jj][r]);
                }
            }
        }
    }
}

// -------- flash attention: 32x32 MFMA, P in-register via permlane32_swap ----
// Round-4 analysis: the old 16x16 structure spent ~72 us/CU on the LDS data
// pipe (448 B/lane/tile: K128 + V128 + P-roundtrip 128 + stage 64) -> 76% LDS
// busy at 94 us. This version removes P from LDS entirely and halves K/V
// fragment traffic:
//  - QK^T as S^T = K.Q^T with mfma_32x32x16: lane's C-col = its own t, so the
//    PV A-fragment needs only a lane<->lane+32 half-exchange: one
//    v_permlane32_swap_b32 per dword pair (VALU pipe, no LDS).
//  - 64 q-rows/wave: K/V frag reads amortize over 2 t-tiles (256 B -> 128 B).
//  - l-sum as f32 VALU adds (lane's regs share one t); rounding unbiased.
//  - K/V double-buffered (32 KB): ONE barrier per tile.
//  - o C-layout has t in regs -> epilogue stores float4 direct to global
//    (per-lane 16 B chunks tile full 128 B rows; L2 merges). No LDS transpose.
// Grid (bh=64, tq=8) = 512 blocks = 2/CU, 8 waves/CU.
// Qw (pre-scaled), Kw: [bh][t][e] ; Vt: [bh][e][t]  (bf16) ; out: fp32 [b][h*64+e][t]
// |q.k*SCL| <= 11.4 -> exp2 never overflows; no max subtraction needed.
__global__ __launch_bounds__(256, 2) void attn_k(const short* __restrict__ Qw,
                                                 const short* __restrict__ Kw,
                                                 const short* __restrict__ Vt,
                                                 float* __restrict__ out) {
    __shared__ __align__(16) char smem[32768];
    short* ldsK = (short*)smem;                 // 2 bufs x [s][e] 64x64 swz (8 KB ea)
    short* ldsV = (short*)(smem + 16384);       // 2 bufs x [e][s] 64x64 swz
    float* ldsL = (float*)smem;                 // epilogue alias: [wave][64] rinv

    int bh = blockIdx.x;
    int t0 = blockIdx.y * 256;
    int b = bh >> 4, h = bh & 15;
    int tid = threadIdx.x, wave = tid >> 6, lane = tid & 63;
    int l31 = lane & 31, b5 = lane >> 5;
    int tw = t0 + 64 * wave;                    // this wave's 64 q-rows

    const short* Qp = Qw + (size_t)bh * T_SZ * DH;
    const short* Kp = Kw + (size_t)bh * T_SZ * DH;
    const short* Vp = Vt + (size_t)bh * DH * T_SZ;

    // reg-staging lane geometry (LOGICAL column group; swz() applied at ds_write)
    int rA = lane >> 3;                // row within an 8-row stripe
    int g8 = lane & 7;

    // Q B-frags: qf[ttile][kk]: t = tw+32*ttile+l31, k = 16*kk+8*b5+e
    short8 qf[2][4];
#pragma unroll
    for (int tt = 0; tt < 2; ++tt)
#pragma unroll
        for (int kk = 0; kk < 4; ++kk)
            qf[tt][kk] = *(const short8*)&Qp[(size_t)(tw + 32 * tt + l31) * DH + 16 * kk + 8 * b5];

    f32x16 o[2][2];                    // [ttile][etile]; C: row=t(regs), col=e(lane)
    float ol[2] = {0.f, 0.f};          // per-lane partial l(t = tw+32tt+l31), own b5-half
#pragma unroll
    for (int tt = 0; tt < 2; ++tt)
#pragma unroll
        for (int et = 0; et < 2; ++et) o[tt][et] = (f32x16)0.0f;

    short8 rk[2], rv[2];               // in-flight K/V tile (16 VGPR)
    auto LOADNEXT = [&](int s) {
#pragma unroll
        for (int it = 0; it < 2; ++it) {
            int row = 16 * wave + 8 * it + rA;
            rk[it] = *(const short8*)&Kp[(size_t)(s + row) * DH + g8 * 8];
            rv[it] = *(const short8*)&Vp[(size_t)row * T_SZ + s + g8 * 8];
        }
    };
    auto WRITESTAGE = [&](int buf) {
        short* Kb = ldsK + buf * 4096;
        short* Vb = ldsV + buf * 4096;
#pragma unroll
        for (int it = 0; it < 2; ++it) {
            int row = 16 * wave + 8 * it + rA;
            *(short8*)&Kb[swz(row, g8)] = rk[it];
            *(short8*)&Vb[swz(row, g8)] = rv[it];
        }
    };

    LOADNEXT(0);
    WRITESTAGE(0);
    __syncthreads();

    for (int s0 = 0; s0 < T_SZ; s0 += 64) {
        int cur = (s0 >> 6) & 1;
        LOADNEXT((s0 + 64) & (T_SZ - 1));          // flies under this tile's compute
        const short* Kc = ldsK + cur * 4096;
        const short* Vc = ldsV + cur * 4096;

        // K A-frags: af[ssub][kk]: s_loc = 32*ssub+l31, k = 16*kk+8*b5+e
        short8 af[2][4];
#pragma unroll
        for (int ss = 0; ss < 2; ++ss)
#pragma unroll
            for (int kk = 0; kk < 4; ++kk)
                af[ss][kk] = *(const short8*)&Kc[swz(32 * ss + l31, 2 * kk + b5)];

        // QK^T + exp2 + pack. z[r] = S^T[s_loc=32ss+(r&3)+8(r>>2)+4b5][t=tw+32tt+l31]
        uint2v u[2][2][4];   // [ttile][ssub][g]: dw0 = P(s=8g+4b5+{0,1}), dw1 = {2,3}
#pragma unroll
        for (int tt = 0; tt < 2; ++tt) {
#pragma unroll
            for (int ss = 0; ss < 2; ++ss) {
                f32x16 z = (f32x16)0.0f;
#pragma unroll
                for (int kk = 0; kk < 4; ++kk)
                    z = __builtin_amdgcn_mfma_f32_32x32x16_bf16(af[ss][kk], qf[tt][kk], z, 0, 0, 0);
#pragma unroll
                for (int g = 0; g < 4; ++g) {
                    float p0 = __builtin_amdgcn_exp2f(z[4 * g + 0]);
                    float p1 = __builtin_amdgcn_exp2f(z[4 * g + 1]);
                    float p2 = __builtin_amdgcn_exp2f(z[4 * g + 2]);
                    float p3 = __builtin_amdgcn_exp2f(z[4 * g + 3]);
                    ol[tt] += (p0 + p1) + (p2 + p3);
                    u[tt][ss][g].x = pack_bf2(p0, p1);
                    u[tt][ss][g].y = pack_bf2(p2, p3);
                }
            }
        }

        // V B-frags: vf[etile][kks]: e = 32*et+l31, s_loc = 16*kks+8*b5+e'
        short8 vf[2][4];
#pragma unroll
        for (int et = 0; et < 2; ++et)
#pragma unroll
            for (int kk = 0; kk < 4; ++kk)
                vf[et][kk] = *(const short8*)&Vc[swz(32 * et + l31, 2 * kk + b5)];

        // PV: build pf[kks] in-register via permlane32_swap, then 2 MFMAs each.
        // pf needs P[t=own col][s = 16kks+8b5+0..7]:
        //   dw0,dw1 from b5=0 lane's chunk g=2(kks&1)+b5t; dw2,dw3 from b5=1 lane.
        // swap(a=u[.][ga], b=u[.][ga+1]): a' = [a.lo|b.lo] -> dw0/1, b' = [a.hi|b.hi] -> dw2/3.
#pragma unroll
        for (int tt = 0; tt < 2; ++tt) {
#pragma unroll
            for (int kks = 0; kks < 4; ++kks) {
                const int ssb = kks >> 1, ga = 2 * (kks & 1);
                unsigned a0 = u[tt][ssb][ga].x,     a1 = u[tt][ssb][ga].y;
                unsigned b0 = u[tt][ssb][ga + 1].x, b1 = u[tt][ssb][ga + 1].y;
                asm("v_permlane32_swap_b32 %0, %1" : "+v"(a0), "+v"(b0));
                asm("v_permlane32_swap_b32 %0, %1" : "+v"(a1), "+v"(b1));
                uint4v up; up.x = a0; up.y = a1; up.z = b0; up.w = b1;
                short8 pf = *(short8*)&up;
                o[tt][0] = __builtin_amdgcn_mfma_f32_32x32x16_bf16(pf, vf[0][kks], o[tt][0], 0, 0, 0);
                o[tt][1] = __builtin_amdgcn_mfma_f32_32x32x16_bf16(pf, vf[1][kks], o[tt][1], 0, 0, 0);
            }
        }

        WRITESTAGE(cur ^ 1);    // vmcnt wait on rk/rv inserted here by compiler
        __syncthreads();        // next tile visible; cur reads done before t+2 overwrites
    }

    // l(t) = ol + partner-half; broadcast rinv into per-wave LDS row (wave-private)
#pragma unroll
    for (int tt = 0; tt < 2; ++tt) {
        float l = ol[tt] + __shfl_xor(ol[tt], 32, 64);
        if (lane < 32) ldsL[wave * 64 + tt * 32 + lane] = 1.0f / l;
    }

    // epilogue: o reg 4g+i is t = tw+32tt+8g+4b5+i, e = 32et+l31 -> float4 direct
#pragma unroll
    for (int tt = 0; tt < 2; ++tt) {
#pragma unroll
        for (int g = 0; g < 4; ++g) {
            float4v ri = *(const float4v*)&ldsL[wave * 64 + tt * 32 + 8 * g + 4 * b5];
#pragma unroll
            for (int et = 0; et < 2; ++et) {
                float4v ov;
#pragma unroll
                for (int i = 0; i < 4; ++i) ov[i] = o[tt][et][4 * g + i] * ri[i];
                *(float4v*)&out[(size_t)(b * DE + h * DH + 32 * et + l31) * T_SZ
                                + tw + 32 * tt + 8 * g + 4 * b5] = ov;
            }
        }
    }
}

extern "C" void kernel_launch(void* const* d_in, const int* in_sizes, int n_in,
                              void* d_out, int out_size, void* d_ws, size_t ws_size,
                              hipStream_t stream) {
    const float* x = (const float*)d_in[0];   // fp32 [B][D][T]
    const float* w = (const float*)d_in[1];   // fp32 [3][H][D][dh]
    float* out = (float*)d_out;               // fp32 [B][D][T]
    char* ws = (char*)d_ws;

    const size_t XT_BYTES = (size_t)B_SZ * T_SZ * DE * 2;       // 16.8 MB (bf16)
    const size_t WT_BYTES = (size_t)3 * NHEADS * DH * DE * 2;   // 6.3 MB
    const size_t QKV_BYTES = (size_t)BH * T_SZ * DH * 2;        // 16.8 MB each

    short* XT = (short*)(ws);
    short* WT = (short*)(ws + XT_BYTES);
    short* Qw = (short*)(ws + XT_BYTES + WT_BYTES);
    short* Kw = (short*)(ws + XT_BYTES + WT_BYTES + QKV_BYTES);
    short* Vt = (short*)(ws + XT_BYTES + WT_BYTES + 2 * QKV_BYTES);

    // x: per-b fp32 [D][T] -> bf16 XT [T][D]
    transpose_k<<<dim3(T_SZ / 64, DE / 64, B_SZ), 256, 0, stream>>>(x, XT, DE, T_SZ);
    // w: per-nh fp32 [D][dh] -> bf16 WT [nh][e][D]
    transpose_k<<<dim3(1, DE / 64, 3 * NHEADS), 256, 0, stream>>>(w, WT, DE, DH);
    qkv_k<<<dim3(64, 24), 256, 0, stream>>>(XT, WT, Qw, Kw, Vt);
    attn_k<<<dim3(BH, T_SZ / 256), 256, 0, stream>>>(Qw, Kw, Vt, out);
}